// Round 10
// baseline (204.801 us; speedup 1.0000x reference)
//
#include <hip/hip_runtime.h>
#include <hip/hip_bf16.h>
#include <math.h>

// ---------------------------------------------------------------------------
// CrossAttention on MI355X (gfx950), bf16 MFMA pipeline, round 10.
//   cast_all: fp32 -> bf16
//   proj_qkv: BM=64 x BN=256 tiles, n-looped per block (grid 128x6=768):
//             activation re-reads halved (xb 2x, cb 4x)
//   attn: R8 structure + K-token sigma-permutation so PV runs on
//         mfma_16x16x32 (full rate); V in chunked LDS; l via ones-x32 MFMA
//   gemm_out: BM=32 x BN=256 (grid 512): O re-read 2x instead of 8x
// ---------------------------------------------------------------------------

typedef __bf16 bf16x8 __attribute__((ext_vector_type(8)));
typedef __bf16 bf16x4 __attribute__((ext_vector_type(4)));
typedef float f32x4 __attribute__((ext_vector_type(4)));

#define QSCALE 0.18033688011112042f  // 0.125 * log2(e)

#if __has_builtin(__builtin_amdgcn_exp2f)
#define EXP2(x) __builtin_amdgcn_exp2f(x)
#else
#define EXP2(x) exp2f(x)
#endif

__device__ __forceinline__ f32x4 mfma32(bf16x8 a, bf16x8 b, f32x4 c) {
  // 16x16x32: A[m=ln][k=qd*8+j], B[n=ln][k=qd*8+j].
  // D: A's m -> (qd*4+rg), B's n -> ln.
  return __builtin_amdgcn_mfma_f32_16x16x32_bf16(a, b, c, 0, 0, 0);
}

// ---------------------------------------------------------------------------
// fp32 -> bf16 cast of all inputs.
// ---------------------------------------------------------------------------
__global__ __launch_bounds__(256) void cast_all(
    const float* __restrict__ x, const float* __restrict__ ctx,
    const float* __restrict__ wq, const float* __restrict__ wk,
    const float* __restrict__ wv, const float* __restrict__ wo,
    __bf16* __restrict__ xb, __bf16* __restrict__ cb,
    __bf16* __restrict__ wqb, __bf16* __restrict__ wkb,
    __bf16* __restrict__ wvb, __bf16* __restrict__ wob) {
  const int B0 = 1048576;
  const int B1 = 2621440;
  const int B2 = 2686976;
  const int B3 = 2785280;
  const int B4 = 2883584;
  const int B5 = 2949120;
  for (int i = blockIdx.x * blockDim.x + threadIdx.x; i < B5;
       i += gridDim.x * blockDim.x) {
    const float* s;
    __bf16* d;
    int off;
    if (i < B0)      { s = x;   d = xb;  off = i; }
    else if (i < B1) { s = ctx; d = cb;  off = i - B0; }
    else if (i < B2) { s = wq;  d = wqb; off = i - B1; }
    else if (i < B3) { s = wk;  d = wkb; off = i - B2; }
    else if (i < B4) { s = wv;  d = wvb; off = i - B3; }
    else             { s = wo;  d = wob; off = i - B4; }
    float4 f = ((const float4*)s)[off];
    union { __bf16 b[4]; ushort4 u; } cv;
    cv.b[0] = (__bf16)f.x; cv.b[1] = (__bf16)f.y;
    cv.b[2] = (__bf16)f.z; cv.b[3] = (__bf16)f.w;
    ((ushort4*)d)[off] = cv.u;
  }
}

// ---------------------------------------------------------------------------
// proj body: 64(tok) x 256(e) tile, C = A * W^T.  4 waves as 2x2 of 32x128.
// Per k-iter: A stage 1x uint4/thread, B stage 4x uint4/thread, 16 mfma/wave.
// MODE 0 (roles swapped): bf16 out [b,h,tok,d], 8B stores over d
// MODE 1 (natural roles): bf16 out [b,h,d,tok], 8B stores over tok
// ---------------------------------------------------------------------------
template <int MODE>
__device__ __forceinline__ void proj_body(
    const __bf16* __restrict__ A, const __bf16* __restrict__ W,
    __bf16* __restrict__ Cout, int Kd, float scale, int m0, int n0,
    __bf16 (*As)[40], __bf16 (*Bs)[40]) {
  const int t = threadIdx.x;
  const int w = t >> 6;
  const int lane = t & 63;
  const int ln = lane & 15;
  const int qd = lane >> 4;
  const int wm = (w >> 1) * 32;   // token offset of wave tile
  const int wn = (w & 1) * 128;   // e offset of wave tile

  f32x4 zero4 = {0.f, 0.f, 0.f, 0.f};
  f32x4 acc[2][8];
#pragma unroll
  for (int i = 0; i < 2; ++i)
#pragma unroll
    for (int j = 0; j < 8; ++j) acc[i][j] = zero4;

  const int ra = t >> 2, ca = (t & 3) * 8;  // A: 64x32, uint4/thread
  const __bf16* gA = A + (size_t)(m0 + ra) * Kd + ca;
  const __bf16* gB = W + (size_t)(n0 + t) * Kd;  // B: 256 rows, row/thread

  for (int kc = 0; kc < Kd; kc += 32) {
    uint4 a0 = *(const uint4*)(gA + kc);
    uint4 b0 = *(const uint4*)(gB + kc);
    uint4 b1 = *(const uint4*)(gB + kc + 8);
    uint4 b2 = *(const uint4*)(gB + kc + 16);
    uint4 b3 = *(const uint4*)(gB + kc + 24);
    __syncthreads();
    *(uint4*)&As[ra][ca] = a0;
    *(uint4*)&Bs[t][0] = b0;
    *(uint4*)&Bs[t][8] = b1;
    *(uint4*)&Bs[t][16] = b2;
    *(uint4*)&Bs[t][24] = b3;
    __syncthreads();
    bf16x8 af[2];
#pragma unroll
    for (int i = 0; i < 2; ++i)
      af[i] = *(const bf16x8*)&As[wm + i * 16 + ln][qd * 8];
#pragma unroll
    for (int j = 0; j < 8; ++j) {
      bf16x8 bfr = *(const bf16x8*)&Bs[wn + j * 16 + ln][qd * 8];
#pragma unroll
      for (int i = 0; i < 2; ++i) {
        if (MODE == 1)
          acc[i][j] = mfma32(af[i], bfr, acc[i][j]);  // tok->(qd,rg), e->ln
        else
          acc[i][j] = mfma32(bfr, af[i], acc[i][j]);  // e->(qd,rg), tok->ln
      }
    }
  }

#pragma unroll
  for (int i = 0; i < 2; ++i)
#pragma unroll
    for (int j = 0; j < 8; ++j) {
      if (MODE == 0) {
        const int gm = m0 + wm + i * 16 + ln;        // token
        const int gn0 = n0 + wn + j * 16 + qd * 4;   // e (4 consecutive)
        const int bb = gm >> 11, tok = gm & 2047;
        const int hh = gn0 >> 6, dd0 = gn0 & 63;
        bf16x4 v;
#pragma unroll
        for (int rg = 0; rg < 4; ++rg) v[rg] = (__bf16)(acc[i][j][rg] * scale);
        *(bf16x4*)(Cout + (((size_t)bb * 8 + hh) * 2048 + tok) * 64 + dd0) = v;
      } else {
        const int gm0 = m0 + wm + i * 16 + qd * 4;   // token (4 consecutive)
        const int gn = n0 + wn + j * 16 + ln;        // e
        const int bb = gm0 >> 11, tok0 = gm0 & 2047;
        const int hh = gn >> 6, dd = gn & 63;
        bf16x4 v;
#pragma unroll
        for (int rg = 0; rg < 4; ++rg) v[rg] = (__bf16)acc[i][j][rg];
        *(bf16x4*)(Cout + (((size_t)bb * 8 + hh) * 64 + dd) * 2048 + tok0) = v;
      }
    }
}

// Fused Q/K/V projections: grid (128, 6) = 768 blocks -> 3 blocks/CU.
// y>>1 = job (0 Q, 1 K, 2 V); y&1 = n-half (256 e-cols each).
__global__ __launch_bounds__(256, 3) void proj_qkv(
    const __bf16* __restrict__ xb, const __bf16* __restrict__ cb,
    const __bf16* __restrict__ Wq, const __bf16* __restrict__ Wk,
    const __bf16* __restrict__ Wv, __bf16* __restrict__ Qw,
    __bf16* __restrict__ Kw, __bf16* __restrict__ Vtw) {
  __shared__ __bf16 As[64][40];    //  5120B
  __shared__ __bf16 Bs[256][40];   // 20480B  -> 25.6KB
  const int m0 = blockIdx.x * 64;
  const int job = blockIdx.y >> 1;
  const int n0 = (blockIdx.y & 1) * 256;
  if (job == 0)
    proj_body<0>(xb, Wq, Qw, 512, QSCALE, m0, n0, As, Bs);
  else if (job == 1)
    proj_body<0>(cb, Wk, Kw, 768, 1.0f, m0, n0, As, Bs);
  else
    proj_body<1>(cb, Wv, Vtw, 768, 1.0f, m0, n0, As, Bs);
}

// ---------------------------------------------------------------------------
// Final GEMM: out = ((O0+O1)/(l0+l1)) Wo^T + bo, fp32.
// BM=32 x BN=256 tiles, grid (256, 2) = 512 blocks -> O re-read only 2x.
// 4 waves as 2x2 of 16x128.  inv(l) hoisted.
// ---------------------------------------------------------------------------
__global__ __launch_bounds__(256, 3) void gemm_out(
    const __bf16* __restrict__ O0, const __bf16* __restrict__ O1,
    const float* __restrict__ lbuf,  // [2][32][2048]
    const __bf16* __restrict__ B,    // Wo bf16 [512 x 512]
    float* __restrict__ C, const float* __restrict__ bias) {
  const int m0 = blockIdx.x * 32;
  const int n0 = blockIdx.y * 256;
  const int t = threadIdx.x;
  const int w = t >> 6;
  const int lane = t & 63;
  const int ln = lane & 15;
  const int qd = lane >> 4;
  const int wm = (w >> 1) * 16;
  const int wn = (w & 1) * 128;

  __shared__ __bf16 As[32][40];    //  2560B
  __shared__ __bf16 Bs[256][40];   // 20480B

  f32x4 zero4 = {0.f, 0.f, 0.f, 0.f};
  f32x4 acc[8];
#pragma unroll
  for (int j = 0; j < 8; ++j) acc[j] = zero4;

  const int ra = t >> 3, ca = (t & 7) * 4;  // A: 32x32, uint2/thread
  const int gm_s = m0 + ra;
  const int bidx = gm_s >> 11, tok_s = gm_s & 2047;
  const size_t aoff = (size_t)gm_s * 512 + ca;
  const __bf16* gB = B + (size_t)(n0 + t) * 512;

  float inv[8];
#pragma unroll
  for (int hh = 0; hh < 8; ++hh) {
    const float l0 = lbuf[((size_t)bidx * 8 + hh) * 2048 + tok_s];
    const float l1 = lbuf[65536 + ((size_t)bidx * 8 + hh) * 2048 + tok_s];
    inv[hh] = 1.0f / (l0 + l1);
  }

  for (int kc = 0; kc < 512; kc += 32) {
    const float iv = inv[kc >> 6];
    union { bf16x4 v; uint2 u; } u0, u1, rr;
    u0.u = *(const uint2*)(O0 + aoff + kc);
    u1.u = *(const uint2*)(O1 + aoff + kc);
    uint4 b0 = *(const uint4*)(gB + kc);
    uint4 b1 = *(const uint4*)(gB + kc + 8);
    uint4 b2 = *(const uint4*)(gB + kc + 16);
    uint4 b3 = *(const uint4*)(gB + kc + 24);
#pragma unroll
    for (int e = 0; e < 4; ++e)
      rr.v[e] = (__bf16)(((float)u0.v[e] + (float)u1.v[e]) * iv);
    __syncthreads();
    *(uint2*)&As[ra][ca] = rr.u;
    *(uint4*)&Bs[t][0] = b0;
    *(uint4*)&Bs[t][8] = b1;
    *(uint4*)&Bs[t][16] = b2;
    *(uint4*)&Bs[t][24] = b3;
    __syncthreads();
    bf16x8 af = *(const bf16x8*)&As[wm + ln][qd * 8];
#pragma unroll
    for (int j = 0; j < 8; ++j) {
      bf16x8 bfr = *(const bf16x8*)&Bs[wn + j * 16 + ln][qd * 8];
      acc[j] = mfma32(bfr, af, acc[j]);  // e->(qd,rg), tok->ln
    }
  }

#pragma unroll
  for (int j = 0; j < 8; ++j) {
    const int gm = m0 + wm + ln;
    const int gn0 = n0 + wn + j * 16 + qd * 4;
    f32x4 bi = *(const f32x4*)&bias[gn0];
    f32x4 v = acc[j] + bi;
    *(f32x4*)&C[(size_t)gm * 512 + gn0] = v;
  }
}

// ---------------------------------------------------------------------------
// Flash attention: S^T trick, raw-exp2 max-free softmax, BQ=128, split-K=2,
// Q in regs.  NEW: K tokens sigma-permuted within 32-chunks at staging so the
// S^T C-layout directly matches the x32 B-frag (k=qd*8+j); V staged in
// chunked LDS [4][64][40] giving natural-order b128 A-frags; PV and the
// l row-sum (all-ones A) run on mfma_16x16x32 -> PV instr count halved.
// ---------------------------------------------------------------------------
__global__ __launch_bounds__(256, 4) void attn_kernel(
    const __bf16* __restrict__ Q,   // [BH][2048][64], pre-scaled by QSCALE
    const __bf16* __restrict__ K,   // [BH][2048][64]
    const __bf16* __restrict__ Vt,  // [BH][64][2048]
    __bf16* __restrict__ Oh,        // [2][B][2048][512] unnormalized
    float* __restrict__ lbuf) {     // [2][BH][2048]
  const int S = 2048;
  const int qt = blockIdx.x;
  const int bh = blockIdx.y;
  const int sp = blockIdx.z;
  const int b = bh >> 3, h = bh & 7;
  const int t = threadIdx.x;
  const int w = t >> 6;
  const int lane = t & 63;
  const int ln = lane & 15;
  const int qd = lane >> 4;

  __shared__ __align__(16) __bf16 Ks[128][72];    // 18432B
  __shared__ __align__(16) __bf16 V4[4][64][40];  // 20480B  total 38912B

  bf16x8 bq[2][2];  // [mt][kst]
  {
    const __bf16* qb =
        Q + ((size_t)bh * S + qt * 128 + w * 32 + ln) * 64 + qd * 8;
#pragma unroll
    for (int mt = 0; mt < 2; ++mt)
#pragma unroll
      for (int kst = 0; kst < 2; ++kst)
        bq[mt][kst] = *(const bf16x8*)(qb + mt * 1024 + kst * 32);
  }

  f32x4 zero4 = {0.f, 0.f, 0.f, 0.f};
  f32x4 o[2][4];
  f32x4 o_l[2];
#pragma unroll
  for (int mt = 0; mt < 2; ++mt) {
#pragma unroll
    for (int i = 0; i < 4; ++i) o[mt][i] = zero4;
    o_l[mt] = zero4;
  }
  bf16x8 ones8;
  {
    union { unsigned short u[8]; bf16x8 v; } U;
#pragma unroll
    for (int e = 0; e < 8; ++e) U.u[e] = 0x3F80;  // bf16 1.0
    ones8 = U.v;
  }

  const int kr = t >> 1, kc = (t & 1) * 32;  // K staging: token kr, col half
  // sigma: token v -> row 16*((v>>2)&1) + 4*(v>>3) + (v&3) within 32-chunk
  const int krow =
      (kr & ~31) | ((kr & 4) << 2) | (((kr >> 3) & 3) << 2) | (kr & 3);
  const int vd = t >> 2, cV = t & 3;         // V staging: d-row, 32-tok chunk
  const int kt0 = sp * 8;

  for (int kt = kt0; kt < kt0 + 8; ++kt) {
    const uint4* gK =
        (const uint4*)(K + ((size_t)bh * S + kt * 128 + kr) * 64 + kc);
    const uint4* gV =
        (const uint4*)(Vt + ((size_t)bh * 64 + vd) * S + kt * 128 + cV * 32);
    uint4 kv0 = gK[0], kv1 = gK[1], kv2 = gK[2], kv3 = gK[3];
    uint4 vv0 = gV[0], vv1 = gV[1], vv2 = gV[2], vv3 = gV[3];
    __syncthreads();
    {
      uint4* dK = (uint4*)&Ks[krow][kc];   // 144B stride: 16B-aligned
      dK[0] = kv0; dK[1] = kv1; dK[2] = kv2; dK[3] = kv3;
      uint4* dV = (uint4*)&V4[cV][vd][0];  // 80B row stride: 16B-aligned
      dV[0] = vv0; dV[1] = vv1; dV[2] = vv2; dV[3] = vv3;
    }
    __syncthreads();

    // per 32-token chunk c: QK (2 tiles) -> exp2 -> x32 PV + ones row-sum
#pragma unroll
    for (int c = 0; c < 4; ++c) {
      f32x4 s[2][2];  // [e][mt]
      s[0][0] = zero4; s[0][1] = zero4; s[1][0] = zero4; s[1][1] = zero4;
#pragma unroll
      for (int e = 0; e < 2; ++e) {
        const int nt = c * 2 + e;
#pragma unroll
        for (int kst = 0; kst < 2; ++kst) {
          bf16x8 ak = *(const bf16x8*)&Ks[nt * 16 + ln][kst * 32 + qd * 8];
          s[e][0] = mfma32(ak, bq[0][kst], s[e][0]);
          s[e][1] = mfma32(ak, bq[1][kst], s[e][1]);
        }
      }
#pragma unroll
      for (int e = 0; e < 2; ++e)
#pragma unroll
        for (int mt = 0; mt < 2; ++mt)
#pragma unroll
          for (int rg = 0; rg < 4; ++rg) s[e][mt][rg] = EXP2(s[e][mt][rg]);
      // pack P as x32 B-frag: lane holds tokens c*32 + qd*8 + j
      // (j<4 from e=0 rg=j; j>=4 from e=1 rg=j-4 -- matches sigma)
      bf16x8 p[2];
#pragma unroll
      for (int mt = 0; mt < 2; ++mt) {
#pragma unroll
        for (int rg = 0; rg < 4; ++rg) {
          p[mt][rg] = (__bf16)s[0][mt][rg];
          p[mt][rg + 4] = (__bf16)s[1][mt][rg];
        }
      }
      o_l[0] = mfma32(ones8, p[0], o_l[0]);
      o_l[1] = mfma32(ones8, p[1], o_l[1]);
#pragma unroll
      for (int i = 0; i < 4; ++i) {
        bf16x8 av = *(const bf16x8*)&V4[c][i * 16 + ln][qd * 8];
        o[0][i] = mfma32(av, p[0], o[0][i]);
        o[1][i] = mfma32(av, p[1], o[1][i]);
      }
    }
  }

  // ---- epilogue: write UNNORMALIZED O + l (combine happens in gemm_out)
  __bf16* Osp = Oh + (size_t)sp * 8192 * 512;
#pragma unroll
  for (int mt = 0; mt < 2; ++mt) {
    const int tok = qt * 128 + w * 32 + mt * 16 + ln;
    if (qd == 0) lbuf[((size_t)sp * 32 + bh) * 2048 + tok] = o_l[mt][0];
#pragma unroll
    for (int i = 0; i < 4; ++i) {
      bf16x4 v;
#pragma unroll
      for (int rg = 0; rg < 4; ++rg) v[rg] = (__bf16)o[mt][i][rg];
      const int col = h * 64 + i * 16 + qd * 4;
      *(bf16x4*)&Osp[((size_t)b * S + tok) * 512 + col] = v;
    }
  }
}

// ---------------------------------------------------------------------------
extern "C" void kernel_launch(void* const* d_in, const int* in_sizes, int n_in,
                              void* d_out, int out_size, void* d_ws,
                              size_t ws_size, hipStream_t stream) {
  const float* x = (const float*)d_in[0];
  const float* ctx = (const float*)d_in[1];
  const float* Wq = (const float*)d_in[2];
  const float* Wk = (const float*)d_in[3];
  const float* Wv = (const float*)d_in[4];
  const float* Wo = (const float*)d_in[5];
  const float* bo = (const float*)d_in[6];

  char* p = (char*)d_ws;
  __bf16* xb = (__bf16*)p;   p += (size_t)8192 * 512 * 2;
  __bf16* cb = (__bf16*)p;   p += (size_t)8192 * 768 * 2;
  __bf16* wqb = (__bf16*)p;  p += (size_t)512 * 512 * 2;
  __bf16* wkb = (__bf16*)p;  p += (size_t)512 * 768 * 2;
  __bf16* wvb = (__bf16*)p;  p += (size_t)512 * 768 * 2;
  __bf16* wob = (__bf16*)p;  p += (size_t)512 * 512 * 2;
  __bf16* Qw = (__bf16*)p;   p += (size_t)8192 * 512 * 2;
  __bf16* Kw = (__bf16*)p;   p += (size_t)8192 * 512 * 2;
  __bf16* Vtw = (__bf16*)p;  p += (size_t)8192 * 512 * 2;
  __bf16* Oh = (__bf16*)p;   p += (size_t)2 * 8192 * 512 * 2;
  float* lbuf = (float*)p;   p += (size_t)2 * 32 * 2048 * 4;

  cast_all<<<2880, 256, 0, stream>>>(x, ctx, Wq, Wk, Wv, Wo, xb, cb, wqb, wkb,
                                     wvb, wob);

  dim3 gp(128, 6);
  proj_qkv<<<gp, 256, 0, stream>>>(xb, cb, wqb, wkb, wvb, Qw, Kw, Vtw);

  dim3 ga(16, 32, 2);
  attn_kernel<<<ga, 256, 0, stream>>>(Qw, Kw, Vtw, Oh, lbuf);

  dim3 go(256, 2);
  gemm_out<<<go, 256, 0, stream>>>(Oh, Oh + (size_t)8192 * 512, lbuf, wob,
                                   (float*)d_out, bo);
}

// Round 11
// 177.456 us; speedup vs baseline: 1.1541x; 1.1541x over previous
//
#include <hip/hip_runtime.h>
#include <hip/hip_bf16.h>
#include <math.h>

// ---------------------------------------------------------------------------
// CrossAttention on MI355X (gfx950), bf16 MFMA pipeline, round 11.
//   cast_all: fp32 -> bf16
//   proj_qkv: 128x128 tile, BK=64 (32 MFMA/barrier), coalesced 4-lane/row
//             staging, register prefetch across the barrier. grid (64,12).
//   attn: R10 kernel VERBATIM (x32 PV via sigma-permuted K rows; <=50us)
//   gemm_out: 64x128 tile, BK=64, same pipeline, combine+inv hoisted.
// ---------------------------------------------------------------------------

typedef __bf16 bf16x8 __attribute__((ext_vector_type(8)));
typedef __bf16 bf16x4 __attribute__((ext_vector_type(4)));
typedef float f32x4 __attribute__((ext_vector_type(4)));

#define QSCALE 0.18033688011112042f  // 0.125 * log2(e)

#if __has_builtin(__builtin_amdgcn_exp2f)
#define EXP2(x) __builtin_amdgcn_exp2f(x)
#else
#define EXP2(x) exp2f(x)
#endif

__device__ __forceinline__ f32x4 mfma32(bf16x8 a, bf16x8 b, f32x4 c) {
  // 16x16x32: A[m=ln][k=qd*8+j], B[n=ln][k=qd*8+j].
  // D: A's m -> (qd*4+rg), B's n -> ln.
  return __builtin_amdgcn_mfma_f32_16x16x32_bf16(a, b, c, 0, 0, 0);
}

// ---------------------------------------------------------------------------
// fp32 -> bf16 cast of all inputs.
// ---------------------------------------------------------------------------
__global__ __launch_bounds__(256) void cast_all(
    const float* __restrict__ x, const float* __restrict__ ctx,
    const float* __restrict__ wq, const float* __restrict__ wk,
    const float* __restrict__ wv, const float* __restrict__ wo,
    __bf16* __restrict__ xb, __bf16* __restrict__ cb,
    __bf16* __restrict__ wqb, __bf16* __restrict__ wkb,
    __bf16* __restrict__ wvb, __bf16* __restrict__ wob) {
  const int B0 = 1048576;
  const int B1 = 2621440;
  const int B2 = 2686976;
  const int B3 = 2785280;
  const int B4 = 2883584;
  const int B5 = 2949120;
  for (int i = blockIdx.x * blockDim.x + threadIdx.x; i < B5;
       i += gridDim.x * blockDim.x) {
    const float* s;
    __bf16* d;
    int off;
    if (i < B0)      { s = x;   d = xb;  off = i; }
    else if (i < B1) { s = ctx; d = cb;  off = i - B0; }
    else if (i < B2) { s = wq;  d = wqb; off = i - B1; }
    else if (i < B3) { s = wk;  d = wkb; off = i - B2; }
    else if (i < B4) { s = wv;  d = wvb; off = i - B3; }
    else             { s = wo;  d = wob; off = i - B4; }
    float4 f = ((const float4*)s)[off];
    union { __bf16 b[4]; ushort4 u; } cv;
    cv.b[0] = (__bf16)f.x; cv.b[1] = (__bf16)f.y;
    cv.b[2] = (__bf16)f.z; cv.b[3] = (__bf16)f.w;
    ((ushort4*)d)[off] = cv.u;
  }
}

// ---------------------------------------------------------------------------
// 128x128 GEMM body, BK=64, register-prefetch pipeline, coalesced staging
// (thread t: rows t>>2 and t>>2+64, cols (t&3)*16 -> 4 lanes cover a row's
// 128B contiguously).  4 waves as 2x2 of 64x64; 32 MFMA per barrier-pair.
// MODE 0 (roles swapped): bf16 out [b,h,tok,d], 8B stores over d
// MODE 1 (natural roles): bf16 out [b,h,d,tok], 8B stores over tok
// ---------------------------------------------------------------------------
template <int MODE>
__device__ __forceinline__ void gemm_body(
    const __bf16* __restrict__ A, const __bf16* __restrict__ W,
    __bf16* __restrict__ Cout, int Kd, float scale, int m0, int n0,
    __bf16 (*As)[72], __bf16 (*Bs)[72]) {
  const int t = threadIdx.x;
  const int w = t >> 6;
  const int lane = t & 63;
  const int ln = lane & 15;
  const int qd = lane >> 4;
  const int wm = (w >> 1) * 64;
  const int wn = (w & 1) * 64;

  f32x4 zero4 = {0.f, 0.f, 0.f, 0.f};
  f32x4 acc[4][4];
#pragma unroll
  for (int i = 0; i < 4; ++i)
#pragma unroll
    for (int j = 0; j < 4; ++j) acc[i][j] = zero4;

  const int r0 = t >> 2;          // 0..63
  const int c0 = (t & 3) * 16;    // 0/16/32/48
  const __bf16* gA0 = A + (size_t)(m0 + r0) * Kd + c0;
  const __bf16* gA1 = A + (size_t)(m0 + r0 + 64) * Kd + c0;
  const __bf16* gB0 = W + (size_t)(n0 + r0) * Kd + c0;
  const __bf16* gB1 = W + (size_t)(n0 + r0 + 64) * Kd + c0;

  // prologue: load tile 0 into registers
  uint4 a00 = *(const uint4*)gA0, a01 = *(const uint4*)(gA0 + 8);
  uint4 a10 = *(const uint4*)gA1, a11 = *(const uint4*)(gA1 + 8);
  uint4 b00 = *(const uint4*)gB0, b01 = *(const uint4*)(gB0 + 8);
  uint4 b10 = *(const uint4*)gB1, b11 = *(const uint4*)(gB1 + 8);

  for (int kc = 0; kc < Kd; kc += 64) {
    __syncthreads();  // previous iteration's frag reads complete
    *(uint4*)&As[r0][c0] = a00;       *(uint4*)&As[r0][c0 + 8] = a01;
    *(uint4*)&As[r0 + 64][c0] = a10;  *(uint4*)&As[r0 + 64][c0 + 8] = a11;
    *(uint4*)&Bs[r0][c0] = b00;       *(uint4*)&Bs[r0][c0 + 8] = b01;
    *(uint4*)&Bs[r0 + 64][c0] = b10;  *(uint4*)&Bs[r0 + 64][c0 + 8] = b11;
    __syncthreads();  // LDS tile ready
    if (kc + 64 < Kd) {  // prefetch next tile: latency hidden behind MFMAs
      a00 = *(const uint4*)(gA0 + kc + 64);
      a01 = *(const uint4*)(gA0 + kc + 72);
      a10 = *(const uint4*)(gA1 + kc + 64);
      a11 = *(const uint4*)(gA1 + kc + 72);
      b00 = *(const uint4*)(gB0 + kc + 64);
      b01 = *(const uint4*)(gB0 + kc + 72);
      b10 = *(const uint4*)(gB1 + kc + 64);
      b11 = *(const uint4*)(gB1 + kc + 72);
    }
#pragma unroll
    for (int kst = 0; kst < 2; ++kst) {
      bf16x8 af[4], bfr[4];
#pragma unroll
      for (int i = 0; i < 4; ++i) {
        af[i] = *(const bf16x8*)&As[wm + i * 16 + ln][kst * 32 + qd * 8];
        bfr[i] = *(const bf16x8*)&Bs[wn + i * 16 + ln][kst * 32 + qd * 8];
      }
#pragma unroll
      for (int i = 0; i < 4; ++i)
#pragma unroll
        for (int j = 0; j < 4; ++j) {
          if (MODE == 1)
            acc[i][j] = mfma32(af[i], bfr[j], acc[i][j]);  // tok->(qd,rg)
          else
            acc[i][j] = mfma32(bfr[j], af[i], acc[i][j]);  // e->(qd,rg)
        }
    }
  }

#pragma unroll
  for (int i = 0; i < 4; ++i)
#pragma unroll
    for (int j = 0; j < 4; ++j) {
      if (MODE == 0) {
        const int gm = m0 + wm + i * 16 + ln;           // token
        const int gn0 = n0 + wn + j * 16 + qd * 4;      // e (4 consecutive)
        const int bb = gm >> 11, tok = gm & 2047;
        const int hh = gn0 >> 6, dd0 = gn0 & 63;
        bf16x4 v;
#pragma unroll
        for (int rg = 0; rg < 4; ++rg) v[rg] = (__bf16)(acc[i][j][rg] * scale);
        *(bf16x4*)(Cout + (((size_t)bb * 8 + hh) * 2048 + tok) * 64 + dd0) = v;
      } else {
        const int gm0 = m0 + wm + i * 16 + qd * 4;      // token (4 consecutive)
        const int gn = n0 + wn + j * 16 + ln;           // e
        const int bb = gm0 >> 11, tok0 = gm0 & 2047;
        const int hh = gn >> 6, dd = gn & 63;
        bf16x4 v;
#pragma unroll
        for (int rg = 0; rg < 4; ++rg) v[rg] = (__bf16)acc[i][j][rg];
        *(bf16x4*)(Cout + (((size_t)bb * 8 + hh) * 64 + dd) * 2048 + tok0) = v;
      }
    }
}

// Fused Q/K/V projections: grid (64, 12) = 768 blocks -> 3 blocks/CU.
__global__ __launch_bounds__(256, 3) void proj_qkv(
    const __bf16* __restrict__ xb, const __bf16* __restrict__ cb,
    const __bf16* __restrict__ Wq, const __bf16* __restrict__ Wk,
    const __bf16* __restrict__ Wv, __bf16* __restrict__ Qw,
    __bf16* __restrict__ Kw, __bf16* __restrict__ Vtw) {
  __shared__ __align__(16) __bf16 As[128][72];  // 18432B
  __shared__ __align__(16) __bf16 Bs[128][72];  // 18432B -> 36.9KB
  const int m0 = blockIdx.x * 128;
  const int job = blockIdx.y >> 2;  // 0=Q, 1=K, 2=V
  const int n0 = (blockIdx.y & 3) * 128;
  if (job == 0)
    gemm_body<0>(xb, Wq, Qw, 512, QSCALE, m0, n0, As, Bs);
  else if (job == 1)
    gemm_body<0>(cb, Wk, Kw, 768, 1.0f, m0, n0, As, Bs);
  else
    gemm_body<1>(cb, Wv, Vtw, 768, 1.0f, m0, n0, As, Bs);
}

// ---------------------------------------------------------------------------
// Final GEMM: out = ((O0+O1)/(l0+l1)) Wo^T + bo, fp32.  64x128 tile, BK=64,
// register-prefetch pipeline, grid (128,4)=512.  inv(l) hoisted; one head
// per 64-col K-block -> single iv per iteration.
// ---------------------------------------------------------------------------
__global__ __launch_bounds__(256) void gemm_out(
    const __bf16* __restrict__ O0, const __bf16* __restrict__ O1,
    const float* __restrict__ lbuf,  // [2][32][2048]
    const __bf16* __restrict__ B,    // Wo bf16 [512 x 512]
    float* __restrict__ C, const float* __restrict__ bias) {
  const int m0 = blockIdx.x * 64;
  const int n0 = blockIdx.y * 128;
  const int t = threadIdx.x;
  const int w = t >> 6;
  const int lane = t & 63;
  const int ln = lane & 15;
  const int qd = lane >> 4;
  const int wm = (w >> 1) * 32;
  const int wn = (w & 1) * 64;

  __shared__ __align__(16) __bf16 As[64][72];   //  9216B
  __shared__ __align__(16) __bf16 Bs[128][72];  // 18432B -> 27.6KB

  f32x4 zero4 = {0.f, 0.f, 0.f, 0.f};
  f32x4 acc[2][4];
#pragma unroll
  for (int i = 0; i < 2; ++i)
#pragma unroll
    for (int j = 0; j < 4; ++j) acc[i][j] = zero4;

  const int r0 = t >> 2;        // 0..63
  const int c0 = (t & 3) * 16;  // 0/16/32/48
  const int gm_s = m0 + r0;
  const int bidx = gm_s >> 11, tok_s = gm_s & 2047;
  const size_t aoff = (size_t)gm_s * 512 + c0;
  const __bf16* gB0 = B + (size_t)(n0 + r0) * 512 + c0;
  const __bf16* gB1 = B + (size_t)(n0 + r0 + 64) * 512 + c0;

  float inv[8];
#pragma unroll
  for (int hh = 0; hh < 8; ++hh) {
    const float l0 = lbuf[((size_t)bidx * 8 + hh) * 2048 + tok_s];
    const float l1 = lbuf[65536 + ((size_t)bidx * 8 + hh) * 2048 + tok_s];
    inv[hh] = 1.0f / (l0 + l1);
  }

  // prologue: load tile 0
  uint4 o00 = *(const uint4*)(O0 + aoff), o01 = *(const uint4*)(O0 + aoff + 8);
  uint4 o10 = *(const uint4*)(O1 + aoff), o11 = *(const uint4*)(O1 + aoff + 8);
  uint4 b00 = *(const uint4*)gB0, b01 = *(const uint4*)(gB0 + 8);
  uint4 b10 = *(const uint4*)gB1, b11 = *(const uint4*)(gB1 + 8);

  for (int kc = 0; kc < 512; kc += 64) {
    const float iv = inv[kc >> 6];
    union { bf16x8 v; uint4 u; } u0, u1, r0v, r1v;
    u0.u = o00; u1.u = o10;
#pragma unroll
    for (int e = 0; e < 8; ++e)
      r0v.v[e] = (__bf16)(((float)u0.v[e] + (float)u1.v[e]) * iv);
    u0.u = o01; u1.u = o11;
#pragma unroll
    for (int e = 0; e < 8; ++e)
      r1v.v[e] = (__bf16)(((float)u0.v[e] + (float)u1.v[e]) * iv);
    __syncthreads();
    *(uint4*)&As[r0][c0] = r0v.u;
    *(uint4*)&As[r0][c0 + 8] = r1v.u;
    *(uint4*)&Bs[r0][c0] = b00;       *(uint4*)&Bs[r0][c0 + 8] = b01;
    *(uint4*)&Bs[r0 + 64][c0] = b10;  *(uint4*)&Bs[r0 + 64][c0 + 8] = b11;
    __syncthreads();
    if (kc + 64 < 512) {
      o00 = *(const uint4*)(O0 + aoff + kc + 64);
      o01 = *(const uint4*)(O0 + aoff + kc + 72);
      o10 = *(const uint4*)(O1 + aoff + kc + 64);
      o11 = *(const uint4*)(O1 + aoff + kc + 72);
      b00 = *(const uint4*)(gB0 + kc + 64);
      b01 = *(const uint4*)(gB0 + kc + 72);
      b10 = *(const uint4*)(gB1 + kc + 64);
      b11 = *(const uint4*)(gB1 + kc + 72);
    }
#pragma unroll
    for (int kst = 0; kst < 2; ++kst) {
      bf16x8 af[2], bfr[4];
#pragma unroll
      for (int i = 0; i < 2; ++i)
        af[i] = *(const bf16x8*)&As[wm + i * 16 + ln][kst * 32 + qd * 8];
#pragma unroll
      for (int j = 0; j < 4; ++j)
        bfr[j] = *(const bf16x8*)&Bs[wn + j * 16 + ln][kst * 32 + qd * 8];
#pragma unroll
      for (int i = 0; i < 2; ++i)
#pragma unroll
        for (int j = 0; j < 4; ++j)
          acc[i][j] = mfma32(bfr[j], af[i], acc[i][j]);  // e->(qd,rg)
    }
  }

#pragma unroll
  for (int i = 0; i < 2; ++i)
#pragma unroll
    for (int j = 0; j < 4; ++j) {
      const int gm = m0 + wm + i * 16 + ln;
      const int gn0 = n0 + wn + j * 16 + qd * 4;
      f32x4 bi = *(const f32x4*)&bias[gn0];
      f32x4 v = acc[i][j] + bi;
      *(f32x4*)&C[(size_t)gm * 512 + gn0] = v;
    }
}

// ---------------------------------------------------------------------------
// Flash attention: R10 kernel VERBATIM (passed, <=50us).
// S^T trick, raw-exp2 max-free softmax, BQ=128, split-K=2, Q in regs,
// sigma-permuted K rows -> x32 PV, V in chunked LDS, ones-x32 l row-sum.
// ---------------------------------------------------------------------------
__global__ __launch_bounds__(256, 4) void attn_kernel(
    const __bf16* __restrict__ Q,   // [BH][2048][64], pre-scaled by QSCALE
    const __bf16* __restrict__ K,   // [BH][2048][64]
    const __bf16* __restrict__ Vt,  // [BH][64][2048]
    __bf16* __restrict__ Oh,        // [2][B][2048][512] unnormalized
    float* __restrict__ lbuf) {     // [2][BH][2048]
  const int S = 2048;
  const int qt = blockIdx.x;
  const int bh = blockIdx.y;
  const int sp = blockIdx.z;
  const int b = bh >> 3, h = bh & 7;
  const int t = threadIdx.x;
  const int w = t >> 6;
  const int lane = t & 63;
  const int ln = lane & 15;
  const int qd = lane >> 4;

  __shared__ __align__(16) __bf16 Ks[128][72];    // 18432B
  __shared__ __align__(16) __bf16 V4[4][64][40];  // 20480B  total 38912B

  bf16x8 bq[2][2];  // [mt][kst]
  {
    const __bf16* qb =
        Q + ((size_t)bh * S + qt * 128 + w * 32 + ln) * 64 + qd * 8;
#pragma unroll
    for (int mt = 0; mt < 2; ++mt)
#pragma unroll
      for (int kst = 0; kst < 2; ++kst)
        bq[mt][kst] = *(const bf16x8*)(qb + mt * 1024 + kst * 32);
  }

  f32x4 zero4 = {0.f, 0.f, 0.f, 0.f};
  f32x4 o[2][4];
  f32x4 o_l[2];
#pragma unroll
  for (int mt = 0; mt < 2; ++mt) {
#pragma unroll
    for (int i = 0; i < 4; ++i) o[mt][i] = zero4;
    o_l[mt] = zero4;
  }
  bf16x8 ones8;
  {
    union { unsigned short u[8]; bf16x8 v; } U;
#pragma unroll
    for (int e = 0; e < 8; ++e) U.u[e] = 0x3F80;  // bf16 1.0
    ones8 = U.v;
  }

  const int kr = t >> 1, kc = (t & 1) * 32;  // K staging: token kr, col half
  // sigma: token v -> row 16*((v>>2)&1) + 4*(v>>3) + (v&3) within 32-chunk
  const int krow =
      (kr & ~31) | ((kr & 4) << 2) | (((kr >> 3) & 3) << 2) | (kr & 3);
  const int vd = t >> 2, cV = t & 3;         // V staging: d-row, 32-tok chunk
  const int kt0 = sp * 8;

  for (int kt = kt0; kt < kt0 + 8; ++kt) {
    const uint4* gK =
        (const uint4*)(K + ((size_t)bh * S + kt * 128 + kr) * 64 + kc);
    const uint4* gV =
        (const uint4*)(Vt + ((size_t)bh * 64 + vd) * S + kt * 128 + cV * 32);
    uint4 kv0 = gK[0], kv1 = gK[1], kv2 = gK[2], kv3 = gK[3];
    uint4 vv0 = gV[0], vv1 = gV[1], vv2 = gV[2], vv3 = gV[3];
    __syncthreads();
    {
      uint4* dK = (uint4*)&Ks[krow][kc];   // 144B stride: 16B-aligned
      dK[0] = kv0; dK[1] = kv1; dK[2] = kv2; dK[3] = kv3;
      uint4* dV = (uint4*)&V4[cV][vd][0];  // 80B row stride: 16B-aligned
      dV[0] = vv0; dV[1] = vv1; dV[2] = vv2; dV[3] = vv3;
    }
    __syncthreads();

    // per 32-token chunk c: QK (2 tiles) -> exp2 -> x32 PV + ones row-sum
#pragma unroll
    for (int c = 0; c < 4; ++c) {
      f32x4 s[2][2];  // [e][mt]
      s[0][0] = zero4; s[0][1] = zero4; s[1][0] = zero4; s[1][1] = zero4;
#pragma unroll
      for (int e = 0; e < 2; ++e) {
        const int nt = c * 2 + e;
#pragma unroll
        for (int kst = 0; kst < 2; ++kst) {
          bf16x8 ak = *(const bf16x8*)&Ks[nt * 16 + ln][kst * 32 + qd * 8];
          s[e][0] = mfma32(ak, bq[0][kst], s[e][0]);
          s[e][1] = mfma32(ak, bq[1][kst], s[e][1]);
        }
      }
#pragma unroll
      for (int e = 0; e < 2; ++e)
#pragma unroll
        for (int mt = 0; mt < 2; ++mt)
#pragma unroll
          for (int rg = 0; rg < 4; ++rg) s[e][mt][rg] = EXP2(s[e][mt][rg]);
      // pack P as x32 B-frag: lane holds tokens c*32 + qd*8 + j
      bf16x8 p[2];
#pragma unroll
      for (int mt = 0; mt < 2; ++mt) {
#pragma unroll
        for (int rg = 0; rg < 4; ++rg) {
          p[mt][rg] = (__bf16)s[0][mt][rg];
          p[mt][rg + 4] = (__bf16)s[1][mt][rg];
        }
      }
      o_l[0] = mfma32(ones8, p[0], o_l[0]);
      o_l[1] = mfma32(ones8, p[1], o_l[1]);
#pragma unroll
      for (int i = 0; i < 4; ++i) {
        bf16x8 av = *(const bf16x8*)&V4[c][i * 16 + ln][qd * 8];
        o[0][i] = mfma32(av, p[0], o[0][i]);
        o[1][i] = mfma32(av, p[1], o[1][i]);
      }
    }
  }

  // ---- epilogue: write UNNORMALIZED O + l (combine happens in gemm_out)
  __bf16* Osp = Oh + (size_t)sp * 8192 * 512;
#pragma unroll
  for (int mt = 0; mt < 2; ++mt) {
    const int tok = qt * 128 + w * 32 + mt * 16 + ln;
    if (qd == 0) lbuf[((size_t)sp * 32 + bh) * 2048 + tok] = o_l[mt][0];
#pragma unroll
    for (int i = 0; i < 4; ++i) {
      bf16x4 v;
#pragma unroll
      for (int rg = 0; rg < 4; ++rg) v[rg] = (__bf16)o[mt][i][rg];
      const int col = h * 64 + i * 16 + qd * 4;
      *(bf16x4*)&Osp[((size_t)b * S + tok) * 512 + col] = v;
    }
  }
}

// ---------------------------------------------------------------------------
extern "C" void kernel_launch(void* const* d_in, const int* in_sizes, int n_in,
                              void* d_out, int out_size, void* d_ws,
                              size_t ws_size, hipStream_t stream) {
  const float* x = (const float*)d_in[0];
  const float* ctx = (const float*)d_in[1];
  const float* Wq = (const float*)d_in[2];
  const float* Wk = (const float*)d_in[3];
  const float* Wv = (const float*)d_in[4];
  const float* Wo = (const float*)d_in[5];
  const float* bo = (const float*)d_in[6];

  char* p = (char*)d_ws;
  __bf16* xb = (__bf16*)p;   p += (size_t)8192 * 512 * 2;
  __bf16* cb = (__bf16*)p;   p += (size_t)8192 * 768 * 2;
  __bf16* wqb = (__bf16*)p;  p += (size_t)512 * 512 * 2;
  __bf16* wkb = (__bf16*)p;  p += (size_t)512 * 768 * 2;
  __bf16* wvb = (__bf16*)p;  p += (size_t)512 * 768 * 2;
  __bf16* wob = (__bf16*)p;  p += (size_t)512 * 512 * 2;
  __bf16* Qw = (__bf16*)p;   p += (size_t)8192 * 512 * 2;
  __bf16* Kw = (__bf16*)p;   p += (size_t)8192 * 512 * 2;
  __bf16* Vtw = (__bf16*)p;  p += (size_t)8192 * 512 * 2;
  __bf16* Oh = (__bf16*)p;   p += (size_t)2 * 8192 * 512 * 2;
  float* lbuf = (float*)p;   p += (size_t)2 * 32 * 2048 * 4;

  cast_all<<<2880, 256, 0, stream>>>(x, ctx, Wq, Wk, Wv, Wo, xb, cb, wqb, wkb,
                                     wvb, wob);

  dim3 gp(64, 12);
  proj_qkv<<<gp, 256, 0, stream>>>(xb, cb, wqb, wkb, wvb, Qw, Kw, Vtw);

  dim3 ga(16, 32, 2);
  attn_kernel<<<ga, 256, 0, stream>>>(Qw, Kw, Vtw, Oh, lbuf);

  dim3 go(128, 4);
  gemm_out<<<go, 256, 0, stream>>>(Oh, Oh + (size_t)8192 * 512, lbuf, wob,
                                   (float*)d_out, bo);
}

// Round 12
// 173.180 us; speedup vs baseline: 1.1826x; 1.0247x over previous
//
#include <hip/hip_runtime.h>
#include <hip/hip_bf16.h>
#include <math.h>

// ---------------------------------------------------------------------------
// CrossAttention on MI355X (gfx950), bf16 MFMA pipeline, round 12.
//   cast_all: fp32 -> bf16
//   proj_qkv: 128x128 tile, BK=64, coalesced staging, register prefetch (R11)
//   attn: R11 structure; V LDS layout V4[4][64][40] -> Vs[64][136]
//         (chunk-plane stride was = 0 mod 128B -> 4-way staging conflicts;
//          272B row stride tiles banks like Ks[128][72])
//   gemm_out: 64x128 tile, BK=64, register prefetch (R11)
// ---------------------------------------------------------------------------

typedef __bf16 bf16x8 __attribute__((ext_vector_type(8)));
typedef __bf16 bf16x4 __attribute__((ext_vector_type(4)));
typedef float f32x4 __attribute__((ext_vector_type(4)));

#define QSCALE 0.18033688011112042f  // 0.125 * log2(e)

#if __has_builtin(__builtin_amdgcn_exp2f)
#define EXP2(x) __builtin_amdgcn_exp2f(x)
#else
#define EXP2(x) exp2f(x)
#endif

__device__ __forceinline__ f32x4 mfma32(bf16x8 a, bf16x8 b, f32x4 c) {
  // 16x16x32: A[m=ln][k=qd*8+j], B[n=ln][k=qd*8+j].
  // D: A's m -> (qd*4+rg), B's n -> ln.
  return __builtin_amdgcn_mfma_f32_16x16x32_bf16(a, b, c, 0, 0, 0);
}

// ---------------------------------------------------------------------------
// fp32 -> bf16 cast of all inputs.
// ---------------------------------------------------------------------------
__global__ __launch_bounds__(256) void cast_all(
    const float* __restrict__ x, const float* __restrict__ ctx,
    const float* __restrict__ wq, const float* __restrict__ wk,
    const float* __restrict__ wv, const float* __restrict__ wo,
    __bf16* __restrict__ xb, __bf16* __restrict__ cb,
    __bf16* __restrict__ wqb, __bf16* __restrict__ wkb,
    __bf16* __restrict__ wvb, __bf16* __restrict__ wob) {
  const int B0 = 1048576;
  const int B1 = 2621440;
  const int B2 = 2686976;
  const int B3 = 2785280;
  const int B4 = 2883584;
  const int B5 = 2949120;
  for (int i = blockIdx.x * blockDim.x + threadIdx.x; i < B5;
       i += gridDim.x * blockDim.x) {
    const float* s;
    __bf16* d;
    int off;
    if (i < B0)      { s = x;   d = xb;  off = i; }
    else if (i < B1) { s = ctx; d = cb;  off = i - B0; }
    else if (i < B2) { s = wq;  d = wqb; off = i - B1; }
    else if (i < B3) { s = wk;  d = wkb; off = i - B2; }
    else if (i < B4) { s = wv;  d = wvb; off = i - B3; }
    else             { s = wo;  d = wob; off = i - B4; }
    float4 f = ((const float4*)s)[off];
    union { __bf16 b[4]; ushort4 u; } cv;
    cv.b[0] = (__bf16)f.x; cv.b[1] = (__bf16)f.y;
    cv.b[2] = (__bf16)f.z; cv.b[3] = (__bf16)f.w;
    ((ushort4*)d)[off] = cv.u;
  }
}

// ---------------------------------------------------------------------------
// 128x128 GEMM body, BK=64, register-prefetch pipeline, coalesced staging.
// MODE 0 (roles swapped): bf16 out [b,h,tok,d], 8B stores over d
// MODE 1 (natural roles): bf16 out [b,h,d,tok], 8B stores over tok
// ---------------------------------------------------------------------------
template <int MODE>
__device__ __forceinline__ void gemm_body(
    const __bf16* __restrict__ A, const __bf16* __restrict__ W,
    __bf16* __restrict__ Cout, int Kd, float scale, int m0, int n0,
    __bf16 (*As)[72], __bf16 (*Bs)[72]) {
  const int t = threadIdx.x;
  const int w = t >> 6;
  const int lane = t & 63;
  const int ln = lane & 15;
  const int qd = lane >> 4;
  const int wm = (w >> 1) * 64;
  const int wn = (w & 1) * 64;

  f32x4 zero4 = {0.f, 0.f, 0.f, 0.f};
  f32x4 acc[4][4];
#pragma unroll
  for (int i = 0; i < 4; ++i)
#pragma unroll
    for (int j = 0; j < 4; ++j) acc[i][j] = zero4;

  const int r0 = t >> 2;          // 0..63
  const int c0 = (t & 3) * 16;    // 0/16/32/48
  const __bf16* gA0 = A + (size_t)(m0 + r0) * Kd + c0;
  const __bf16* gA1 = A + (size_t)(m0 + r0 + 64) * Kd + c0;
  const __bf16* gB0 = W + (size_t)(n0 + r0) * Kd + c0;
  const __bf16* gB1 = W + (size_t)(n0 + r0 + 64) * Kd + c0;

  // prologue: load tile 0 into registers
  uint4 a00 = *(const uint4*)gA0, a01 = *(const uint4*)(gA0 + 8);
  uint4 a10 = *(const uint4*)gA1, a11 = *(const uint4*)(gA1 + 8);
  uint4 b00 = *(const uint4*)gB0, b01 = *(const uint4*)(gB0 + 8);
  uint4 b10 = *(const uint4*)gB1, b11 = *(const uint4*)(gB1 + 8);

  for (int kc = 0; kc < Kd; kc += 64) {
    __syncthreads();  // previous iteration's frag reads complete
    *(uint4*)&As[r0][c0] = a00;       *(uint4*)&As[r0][c0 + 8] = a01;
    *(uint4*)&As[r0 + 64][c0] = a10;  *(uint4*)&As[r0 + 64][c0 + 8] = a11;
    *(uint4*)&Bs[r0][c0] = b00;       *(uint4*)&Bs[r0][c0 + 8] = b01;
    *(uint4*)&Bs[r0 + 64][c0] = b10;  *(uint4*)&Bs[r0 + 64][c0 + 8] = b11;
    __syncthreads();  // LDS tile ready
    if (kc + 64 < Kd) {  // prefetch next tile: latency hidden behind MFMAs
      a00 = *(const uint4*)(gA0 + kc + 64);
      a01 = *(const uint4*)(gA0 + kc + 72);
      a10 = *(const uint4*)(gA1 + kc + 64);
      a11 = *(const uint4*)(gA1 + kc + 72);
      b00 = *(const uint4*)(gB0 + kc + 64);
      b01 = *(const uint4*)(gB0 + kc + 72);
      b10 = *(const uint4*)(gB1 + kc + 64);
      b11 = *(const uint4*)(gB1 + kc + 72);
    }
#pragma unroll
    for (int kst = 0; kst < 2; ++kst) {
      bf16x8 af[4], bfr[4];
#pragma unroll
      for (int i = 0; i < 4; ++i) {
        af[i] = *(const bf16x8*)&As[wm + i * 16 + ln][kst * 32 + qd * 8];
        bfr[i] = *(const bf16x8*)&Bs[wn + i * 16 + ln][kst * 32 + qd * 8];
      }
#pragma unroll
      for (int i = 0; i < 4; ++i)
#pragma unroll
        for (int j = 0; j < 4; ++j) {
          if (MODE == 1)
            acc[i][j] = mfma32(af[i], bfr[j], acc[i][j]);  // tok->(qd,rg)
          else
            acc[i][j] = mfma32(bfr[j], af[i], acc[i][j]);  // e->(qd,rg)
        }
    }
  }

#pragma unroll
  for (int i = 0; i < 4; ++i)
#pragma unroll
    for (int j = 0; j < 4; ++j) {
      if (MODE == 0) {
        const int gm = m0 + wm + i * 16 + ln;           // token
        const int gn0 = n0 + wn + j * 16 + qd * 4;      // e (4 consecutive)
        const int bb = gm >> 11, tok = gm & 2047;
        const int hh = gn0 >> 6, dd0 = gn0 & 63;
        bf16x4 v;
#pragma unroll
        for (int rg = 0; rg < 4; ++rg) v[rg] = (__bf16)(acc[i][j][rg] * scale);
        *(bf16x4*)(Cout + (((size_t)bb * 8 + hh) * 2048 + tok) * 64 + dd0) = v;
      } else {
        const int gm0 = m0 + wm + i * 16 + qd * 4;      // token (4 consecutive)
        const int gn = n0 + wn + j * 16 + ln;           // e
        const int bb = gm0 >> 11, tok0 = gm0 & 2047;
        const int hh = gn >> 6, dd = gn & 63;
        bf16x4 v;
#pragma unroll
        for (int rg = 0; rg < 4; ++rg) v[rg] = (__bf16)acc[i][j][rg];
        *(bf16x4*)(Cout + (((size_t)bb * 8 + hh) * 64 + dd) * 2048 + tok0) = v;
      }
    }
}

// Fused Q/K/V projections: grid (64, 12) = 768 blocks -> 3 blocks/CU.
__global__ __launch_bounds__(256, 3) void proj_qkv(
    const __bf16* __restrict__ xb, const __bf16* __restrict__ cb,
    const __bf16* __restrict__ Wq, const __bf16* __restrict__ Wk,
    const __bf16* __restrict__ Wv, __bf16* __restrict__ Qw,
    __bf16* __restrict__ Kw, __bf16* __restrict__ Vtw) {
  __shared__ __align__(16) __bf16 As[128][72];  // 18432B
  __shared__ __align__(16) __bf16 Bs[128][72];  // 18432B -> 36.9KB
  const int m0 = blockIdx.x * 128;
  const int job = blockIdx.y >> 2;  // 0=Q, 1=K, 2=V
  const int n0 = (blockIdx.y & 3) * 128;
  if (job == 0)
    gemm_body<0>(xb, Wq, Qw, 512, QSCALE, m0, n0, As, Bs);
  else if (job == 1)
    gemm_body<0>(cb, Wk, Kw, 768, 1.0f, m0, n0, As, Bs);
  else
    gemm_body<1>(cb, Wv, Vtw, 768, 1.0f, m0, n0, As, Bs);
}

// ---------------------------------------------------------------------------
// Final GEMM: out = ((O0+O1)/(l0+l1)) Wo^T + bo, fp32.  64x128 tile, BK=64,
// register-prefetch pipeline, grid (128,4)=512.  inv(l) hoisted.
// ---------------------------------------------------------------------------
__global__ __launch_bounds__(256) void gemm_out(
    const __bf16* __restrict__ O0, const __bf16* __restrict__ O1,
    const float* __restrict__ lbuf,  // [2][32][2048]
    const __bf16* __restrict__ B,    // Wo bf16 [512 x 512]
    float* __restrict__ C, const float* __restrict__ bias) {
  const int m0 = blockIdx.x * 64;
  const int n0 = blockIdx.y * 128;
  const int t = threadIdx.x;
  const int w = t >> 6;
  const int lane = t & 63;
  const int ln = lane & 15;
  const int qd = lane >> 4;
  const int wm = (w >> 1) * 32;
  const int wn = (w & 1) * 64;

  __shared__ __align__(16) __bf16 As[64][72];   //  9216B
  __shared__ __align__(16) __bf16 Bs[128][72];  // 18432B -> 27.6KB

  f32x4 zero4 = {0.f, 0.f, 0.f, 0.f};
  f32x4 acc[2][4];
#pragma unroll
  for (int i = 0; i < 2; ++i)
#pragma unroll
    for (int j = 0; j < 4; ++j) acc[i][j] = zero4;

  const int r0 = t >> 2;        // 0..63
  const int c0 = (t & 3) * 16;  // 0/16/32/48
  const int gm_s = m0 + r0;
  const int bidx = gm_s >> 11, tok_s = gm_s & 2047;
  const size_t aoff = (size_t)gm_s * 512 + c0;
  const __bf16* gB0 = B + (size_t)(n0 + r0) * 512 + c0;
  const __bf16* gB1 = B + (size_t)(n0 + r0 + 64) * 512 + c0;

  float inv[8];
#pragma unroll
  for (int hh = 0; hh < 8; ++hh) {
    const float l0 = lbuf[((size_t)bidx * 8 + hh) * 2048 + tok_s];
    const float l1 = lbuf[65536 + ((size_t)bidx * 8 + hh) * 2048 + tok_s];
    inv[hh] = 1.0f / (l0 + l1);
  }

  // prologue: load tile 0
  uint4 o00 = *(const uint4*)(O0 + aoff), o01 = *(const uint4*)(O0 + aoff + 8);
  uint4 o10 = *(const uint4*)(O1 + aoff), o11 = *(const uint4*)(O1 + aoff + 8);
  uint4 b00 = *(const uint4*)gB0, b01 = *(const uint4*)(gB0 + 8);
  uint4 b10 = *(const uint4*)gB1, b11 = *(const uint4*)(gB1 + 8);

  for (int kc = 0; kc < 512; kc += 64) {
    const float iv = inv[kc >> 6];
    union { bf16x8 v; uint4 u; } u0, u1, r0v, r1v;
    u0.u = o00; u1.u = o10;
#pragma unroll
    for (int e = 0; e < 8; ++e)
      r0v.v[e] = (__bf16)(((float)u0.v[e] + (float)u1.v[e]) * iv);
    u0.u = o01; u1.u = o11;
#pragma unroll
    for (int e = 0; e < 8; ++e)
      r1v.v[e] = (__bf16)(((float)u0.v[e] + (float)u1.v[e]) * iv);
    __syncthreads();
    *(uint4*)&As[r0][c0] = r0v.u;
    *(uint4*)&As[r0][c0 + 8] = r1v.u;
    *(uint4*)&Bs[r0][c0] = b00;       *(uint4*)&Bs[r0][c0 + 8] = b01;
    *(uint4*)&Bs[r0 + 64][c0] = b10;  *(uint4*)&Bs[r0 + 64][c0 + 8] = b11;
    __syncthreads();
    if (kc + 64 < 512) {
      o00 = *(const uint4*)(O0 + aoff + kc + 64);
      o01 = *(const uint4*)(O0 + aoff + kc + 72);
      o10 = *(const uint4*)(O1 + aoff + kc + 64);
      o11 = *(const uint4*)(O1 + aoff + kc + 72);
      b00 = *(const uint4*)(gB0 + kc + 64);
      b01 = *(const uint4*)(gB0 + kc + 72);
      b10 = *(const uint4*)(gB1 + kc + 64);
      b11 = *(const uint4*)(gB1 + kc + 72);
    }
#pragma unroll
    for (int kst = 0; kst < 2; ++kst) {
      bf16x8 af[2], bfr[4];
#pragma unroll
      for (int i = 0; i < 2; ++i)
        af[i] = *(const bf16x8*)&As[wm + i * 16 + ln][kst * 32 + qd * 8];
#pragma unroll
      for (int j = 0; j < 4; ++j)
        bfr[j] = *(const bf16x8*)&Bs[wn + j * 16 + ln][kst * 32 + qd * 8];
#pragma unroll
      for (int i = 0; i < 2; ++i)
#pragma unroll
        for (int j = 0; j < 4; ++j)
          acc[i][j] = mfma32(bfr[j], af[i], acc[i][j]);  // e->(qd,rg)
    }
  }

#pragma unroll
  for (int i = 0; i < 2; ++i)
#pragma unroll
    for (int j = 0; j < 4; ++j) {
      const int gm = m0 + wm + i * 16 + ln;
      const int gn0 = n0 + wn + j * 16 + qd * 4;
      f32x4 bi = *(const f32x4*)&bias[gn0];
      f32x4 v = acc[i][j] + bi;
      *(f32x4*)&C[(size_t)gm * 512 + gn0] = v;
    }
}

// ---------------------------------------------------------------------------
// Flash attention: S^T trick, raw-exp2 max-free softmax, BQ=128, split-K=2,
// Q in regs, sigma-permuted K rows -> x32 PV, ones-x32 l row-sum.
// R12: V LDS layout Vs[64][136] (272B row stride tiles 32 banks across
// 8-lane groups on b128 reads; staging writes at worst 2-way = free).
// ---------------------------------------------------------------------------
__global__ __launch_bounds__(256, 4) void attn_kernel(
    const __bf16* __restrict__ Q,   // [BH][2048][64], pre-scaled by QSCALE
    const __bf16* __restrict__ K,   // [BH][2048][64]
    const __bf16* __restrict__ Vt,  // [BH][64][2048]
    __bf16* __restrict__ Oh,        // [2][B][2048][512] unnormalized
    float* __restrict__ lbuf) {     // [2][BH][2048]
  const int S = 2048;
  const int qt = blockIdx.x;
  const int bh = blockIdx.y;
  const int sp = blockIdx.z;
  const int b = bh >> 3, h = bh & 7;
  const int t = threadIdx.x;
  const int w = t >> 6;
  const int lane = t & 63;
  const int ln = lane & 15;
  const int qd = lane >> 4;

  __shared__ __align__(16) __bf16 Ks[128][72];   // 18432B
  __shared__ __align__(16) __bf16 Vs[64][136];   // 17408B  total 35840B

  bf16x8 bq[2][2];  // [mt][kst]
  {
    const __bf16* qb =
        Q + ((size_t)bh * S + qt * 128 + w * 32 + ln) * 64 + qd * 8;
#pragma unroll
    for (int mt = 0; mt < 2; ++mt)
#pragma unroll
      for (int kst = 0; kst < 2; ++kst)
        bq[mt][kst] = *(const bf16x8*)(qb + mt * 1024 + kst * 32);
  }

  f32x4 zero4 = {0.f, 0.f, 0.f, 0.f};
  f32x4 o[2][4];
  f32x4 o_l[2];
#pragma unroll
  for (int mt = 0; mt < 2; ++mt) {
#pragma unroll
    for (int i = 0; i < 4; ++i) o[mt][i] = zero4;
    o_l[mt] = zero4;
  }
  bf16x8 ones8;
  {
    union { unsigned short u[8]; bf16x8 v; } U;
#pragma unroll
    for (int e = 0; e < 8; ++e) U.u[e] = 0x3F80;  // bf16 1.0
    ones8 = U.v;
  }

  const int kr = t >> 1, kc = (t & 1) * 32;  // K staging: token kr, col half
  // sigma: token v -> row 16*((v>>2)&1) + 4*(v>>3) + (v&3) within 32-chunk
  const int krow =
      (kr & ~31) | ((kr & 4) << 2) | (((kr >> 3) & 3) << 2) | (kr & 3);
  const int vd = t >> 2, cV = t & 3;         // V staging: d-row, 32-tok chunk
  const int kt0 = sp * 8;

  for (int kt = kt0; kt < kt0 + 8; ++kt) {
    const uint4* gK =
        (const uint4*)(K + ((size_t)bh * S + kt * 128 + kr) * 64 + kc);
    const uint4* gV =
        (const uint4*)(Vt + ((size_t)bh * 64 + vd) * S + kt * 128 + cV * 32);
    uint4 kv0 = gK[0], kv1 = gK[1], kv2 = gK[2], kv3 = gK[3];
    uint4 vv0 = gV[0], vv1 = gV[1], vv2 = gV[2], vv3 = gV[3];
    __syncthreads();
    {
      uint4* dK = (uint4*)&Ks[krow][kc];    // 144B stride: 16B-aligned
      dK[0] = kv0; dK[1] = kv1; dK[2] = kv2; dK[3] = kv3;
      uint4* dV = (uint4*)&Vs[vd][cV * 32]; // 272B stride: 16B-aligned
      dV[0] = vv0; dV[1] = vv1; dV[2] = vv2; dV[3] = vv3;
    }
    __syncthreads();

    // per 32-token chunk c: QK (2 tiles) -> exp2 -> x32 PV + ones row-sum
#pragma unroll
    for (int c = 0; c < 4; ++c) {
      f32x4 s[2][2];  // [e][mt]
      s[0][0] = zero4; s[0][1] = zero4; s[1][0] = zero4; s[1][1] = zero4;
#pragma unroll
      for (int e = 0; e < 2; ++e) {
        const int nt = c * 2 + e;
#pragma unroll
        for (int kst = 0; kst < 2; ++kst) {
          bf16x8 ak = *(const bf16x8*)&Ks[nt * 16 + ln][kst * 32 + qd * 8];
          s[e][0] = mfma32(ak, bq[0][kst], s[e][0]);
          s[e][1] = mfma32(ak, bq[1][kst], s[e][1]);
        }
      }
#pragma unroll
      for (int e = 0; e < 2; ++e)
#pragma unroll
        for (int mt = 0; mt < 2; ++mt)
#pragma unroll
          for (int rg = 0; rg < 4; ++rg) s[e][mt][rg] = EXP2(s[e][mt][rg]);
      // pack P as x32 B-frag: lane holds tokens c*32 + qd*8 + j
      bf16x8 p[2];
#pragma unroll
      for (int mt = 0; mt < 2; ++mt) {
#pragma unroll
        for (int rg = 0; rg < 4; ++rg) {
          p[mt][rg] = (__bf16)s[0][mt][rg];
          p[mt][rg + 4] = (__bf16)s[1][mt][rg];
        }
      }
      o_l[0] = mfma32(ones8, p[0], o_l[0]);
      o_l[1] = mfma32(ones8, p[1], o_l[1]);
#pragma unroll
      for (int i = 0; i < 4; ++i) {
        bf16x8 av = *(const bf16x8*)&Vs[i * 16 + ln][c * 32 + qd * 8];
        o[0][i] = mfma32(av, p[0], o[0][i]);
        o[1][i] = mfma32(av, p[1], o[1][i]);
      }
    }
  }

  // ---- epilogue: write UNNORMALIZED O + l (combine happens in gemm_out)
  __bf16* Osp = Oh + (size_t)sp * 8192 * 512;
#pragma unroll
  for (int mt = 0; mt < 2; ++mt) {
    const int tok = qt * 128 + w * 32 + mt * 16 + ln;
    if (qd == 0) lbuf[((size_t)sp * 32 + bh) * 2048 + tok] = o_l[mt][0];
#pragma unroll
    for (int i = 0; i < 4; ++i) {
      bf16x4 v;
#pragma unroll
      for (int rg = 0; rg < 4; ++rg) v[rg] = (__bf16)o[mt][i][rg];
      const int col = h * 64 + i * 16 + qd * 4;
      *(bf16x4*)&Osp[((size_t)b * S + tok) * 512 + col] = v;
    }
  }
}

// ---------------------------------------------------------------------------
extern "C" void kernel_launch(void* const* d_in, const int* in_sizes, int n_in,
                              void* d_out, int out_size, void* d_ws,
                              size_t ws_size, hipStream_t stream) {
  const float* x = (const float*)d_in[0];
  const float* ctx = (const float*)d_in[1];
  const float* Wq = (const float*)d_in[2];
  const float* Wk = (const float*)d_in[3];
  const float* Wv = (const float*)d_in[4];
  const float* Wo = (const float*)d_in[5];
  const float* bo = (const float*)d_in[6];

  char* p = (char*)d_ws;
  __bf16* xb = (__bf16*)p;   p += (size_t)8192 * 512 * 2;
  __bf16* cb = (__bf16*)p;   p += (size_t)8192 * 768 * 2;
  __bf16* wqb = (__bf16*)p;  p += (size_t)512 * 512 * 2;
  __bf16* wkb = (__bf16*)p;  p += (size_t)512 * 768 * 2;
  __bf16* wvb = (__bf16*)p;  p += (size_t)512 * 768 * 2;
  __bf16* wob = (__bf16*)p;  p += (size_t)512 * 512 * 2;
  __bf16* Qw = (__bf16*)p;   p += (size_t)8192 * 512 * 2;
  __bf16* Kw = (__bf16*)p;   p += (size_t)8192 * 512 * 2;
  __bf16* Vtw = (__bf16*)p;  p += (size_t)8192 * 512 * 2;
  __bf16* Oh = (__bf16*)p;   p += (size_t)2 * 8192 * 512 * 2;
  float* lbuf = (float*)p;   p += (size_t)2 * 32 * 2048 * 4;

  cast_all<<<2880, 256, 0, stream>>>(x, ctx, Wq, Wk, Wv, Wo, xb, cb, wqb, wkb,
                                     wvb, wob);

  dim3 gp(64, 12);
  proj_qkv<<<gp, 256, 0, stream>>>(xb, cb, wqb, wkb, wvb, Qw, Kw, Vtw);

  dim3 ga(16, 32, 2);
  attn_kernel<<<ga, 256, 0, stream>>>(Qw, Kw, Vtw, Oh, lbuf);

  dim3 go(128, 4);
  gemm_out<<<go, 256, 0, stream>>>(Oh, Oh + (size_t)8192 * 512, lbuf, wob,
                                   (float*)d_out, bo);
}